// Round 11
// baseline (4036.631 us; speedup 1.0000x reference)
//
#include <hip/hip_runtime.h>
#include <hip/hip_cooperative_groups.h>
#include <math.h>

namespace cg = cooperative_groups;

#define DTOK 1222
#define NBOU 80
#define MM   160
#define FFD  2048
#define OQKV 3666

#define T1c 39
#define T2c 64
#define NT_IPc 58
#define NT_OPc 20
#define NT_L1c 32
#define NT_L2c 20
#define S_IPc 6
#define S_OPc 10
#define S_L1c 8
#define S_L2c 16

typedef __attribute__((ext_vector_type(8))) short short8;
typedef __attribute__((ext_vector_type(4))) float f32x4;

// ---------- bf16 helpers ----------
__device__ __forceinline__ unsigned short f2bf(float x) {
  unsigned int u = __float_as_uint(x);
  unsigned int r = (u + 0x7FFFu + ((u >> 16) & 1u)) >> 16;
  return (unsigned short)r;
}
__device__ __forceinline__ float bf2f(unsigned short h) {
  return __uint_as_float((unsigned int)h << 16);
}

// ---------- reduction helpers ----------
__device__ __forceinline__ float wave_red_sum(float v) {
#pragma unroll
  for (int off = 32; off; off >>= 1) v += __shfl_xor(v, off, 64);
  return v;
}
__device__ __forceinline__ float block_red_sum(float v, float* rb, int tid) {
  v = wave_red_sum(v);
  __syncthreads();
  if ((tid & 63) == 0) rb[tid >> 6] = v;
  __syncthreads();
  return rb[0] + rb[1] + rb[2] + rb[3];
}

// ---------- frag-write ----------
__device__ __forceinline__ void frag_write_row(const float* __restrict__ row,
                                               short* __restrict__ Af,
                                               int r, int T, int tid) {
  int mt = r >> 6, mf = (r >> 4) & 3, rl = r & 15;
  for (int task = tid; task < T * 4; task += 256) {
    int t = task >> 2, kq = task & 3;
    const float* src = row + t * 32 + kq * 8;
    short8 h, l, q;
#pragma unroll
    for (int j = 0; j < 8; ++j) {
      float x = src[j];
      unsigned short hb = f2bf(x);
      float r1 = x - bf2f(hb);
      unsigned short lb = f2bf(r1);
      float r2 = r1 - bf2f(lb);
      h[j] = (short)hb; l[j] = (short)lb; q[j] = (short)f2bf(r2);
    }
    size_t base = (size_t)(mt * T + t) * 6144 + mf * 512 + (size_t)(rl + kq * 16) * 8;
    *(short8*)(Af + base) = h;
    *(short8*)(Af + base + 2048) = l;
    *(short8*)(Af + base + 4096) = q;
  }
}

// ---------- setup: fused NCHW->NHWC transpose + pool L1 ----------
__global__ __launch_bounds__(256) void k_nhwc0p(const float* __restrict__ f,
                                                float* __restrict__ L0n,
                                                float* __restrict__ L1) {
  int xt = blockIdx.x, y1 = blockIdx.y, zc = blockIdx.z;
  int b = zc >> 4, ct = zc & 15;
  __shared__ float tile[64][65];
  int tid = threadIdx.x;
  const float* fb = f + (size_t)b * 1024 * 50176;
#pragma unroll
  for (int i = 0; i < 16; ++i) {
    int u = tid + 256 * i;
    int xl = u & 31, r = (u >> 5) & 1, c = u >> 6;
    tile[c][xl + 32 * r] = fb[(size_t)(ct * 64 + c) * 50176 +
                              (size_t)(2 * y1 + r) * 224 + xt * 32 + xl];
  }
  __syncthreads();
#pragma unroll
  for (int i = 0; i < 16; ++i) {
    int u = tid + 256 * i;
    int c2 = u & 63, x2 = (u >> 6) & 31, r2 = u >> 11;
    L0n[(((size_t)b * 224 + 2 * y1 + r2) * 224 + xt * 32 + x2) * 1024 + ct * 64 + c2] =
        tile[c2][x2 + 32 * r2];
  }
#pragma unroll
  for (int i = 0; i < 4; ++i) {
    int u = tid + 256 * i;
    int c3 = u & 63, xp = u >> 6;
    float v = 0.25f * (tile[c3][2 * xp] + tile[c3][2 * xp + 1] +
                       tile[c3][32 + 2 * xp] + tile[c3][32 + 2 * xp + 1]);
    L1[(((size_t)b * 112 + y1) * 112 + xt * 16 + xp) * 1024 + ct * 64 + c3] = v;
  }
}

// ---------- setup: fused L1 -> L2, L3 ----------
__global__ __launch_bounds__(256) void k_pool23(const float* __restrict__ L1,
                                                float* __restrict__ L2,
                                                float* __restrict__ L3) {
  int x3 = blockIdx.x, y3 = blockIdx.y, b = blockIdx.z;
  int c = threadIdx.x * 4;
  float4 l2v[2][2];
#pragma unroll
  for (int yy = 0; yy < 2; ++yy)
#pragma unroll
    for (int xx = 0; xx < 2; ++xx) {
      const float* p00 = L1 + (((size_t)(b * 112 + 4 * y3 + 2 * yy) * 112) + 4 * x3 + 2 * xx) * 1024 + c;
      const float* p01 = p00 + 1024;
      const float* p10 = p00 + (size_t)112 * 1024;
      const float* p11 = p10 + 1024;
      float4 a = *(const float4*)p00, bv = *(const float4*)p01;
      float4 cv = *(const float4*)p10, dv = *(const float4*)p11;
      float4 r;
      r.x = 0.25f * (a.x + bv.x + cv.x + dv.x);
      r.y = 0.25f * (a.y + bv.y + cv.y + dv.y);
      r.z = 0.25f * (a.z + bv.z + cv.z + dv.z);
      r.w = 0.25f * (a.w + bv.w + cv.w + dv.w);
      l2v[yy][xx] = r;
      *(float4*)(L2 + (((size_t)(b * 56 + 2 * y3 + yy) * 56) + 2 * x3 + xx) * 1024 + c) = r;
    }
  float4 r3;
  r3.x = 0.25f * (l2v[0][0].x + l2v[0][1].x + l2v[1][0].x + l2v[1][1].x);
  r3.y = 0.25f * (l2v[0][0].y + l2v[0][1].y + l2v[1][0].y + l2v[1][1].y);
  r3.z = 0.25f * (l2v[0][0].z + l2v[0][1].z + l2v[1][0].z + l2v[1][1].z);
  r3.w = 0.25f * (l2v[0][0].w + l2v[0][1].w + l2v[1][0].w + l2v[1][1].w);
  *(float4*)(L3 + (((size_t)(b * 28 + y3) * 28) + x3) * 1024 + c) = r3;
}

// ---------- setup: pe + boundary init ----------
__global__ __launch_bounds__(256) void k_pe(float* __restrict__ pe, int* __restrict__ bnd,
                                            const int* __restrict__ pb) {
  int n = blockIdx.x, tid = threadIdx.x;
  for (int d = tid; d < DTOK; d += 256) {
    int i = d >> 1;
    double e = exp((double)(2 * i) * (-log(10000.0) / (double)DTOK));
    double ang = (double)n * e;
    pe[n * DTOK + d] = (float)((d & 1) ? cos(ang) : sin(ang));
  }
  if (n == 0) {
    for (int t = tid; t < 2 * NBOU * 2; t += 256) bnd[t] = pb[t];
  }
}

// ---------- weight conversion ----------
__global__ __launch_bounds__(256) void k_conv(const float* __restrict__ X,
                                              short* __restrict__ F,
                                              int R, int K, int T) {
  int b = blockIdx.x;
  int rt = b / T, t = b % T;
  int tid = threadIdx.x, mf = tid >> 6, lane = tid & 63;
  int row = rt * 64 + mf * 16 + (lane & 15);
  int k0 = t * 32 + (lane >> 4) * 8;
  float a[8];
#pragma unroll
  for (int j = 0; j < 8; ++j) {
    int k = k0 + j;
    a[j] = (row < R && k < K) ? X[(size_t)row * K + k] : 0.f;
  }
  short8 h, l, q;
#pragma unroll
  for (int j = 0; j < 8; ++j) {
    float x = a[j];
    unsigned short hb = f2bf(x);
    float r1 = x - bf2f(hb);
    unsigned short lb = f2bf(r1);
    float r2 = r1 - bf2f(lb);
    h[j] = (short)hb; l[j] = (short)lb; q[j] = (short)f2bf(r2);
  }
  size_t base = (size_t)b * 6144 + mf * 512 + (size_t)lane * 8;
  *(short8*)(F + base) = h;
  *(short8*)(F + base + 2048) = l;
  *(short8*)(F + base + 4096) = q;
}

// ================== shared phase bodies (grid-agnostic) ==================
struct Params {
  const float *L0n, *L1, *L2, *L3;
  const float *lng, *lnb, *pe;
  const float *ipb, *opb, *l1b, *l2b;
  const float *n1g, *n1b, *n2g, *n2b;
  const float *fcw, *fcb;
  const short *ipWf, *opWf, *l1Wf, *l2Wf;
  short *Af1, *Af2;
  float *tokens, *qkvb, *x1, *dots, *part;
  int *bnd, *outp;
};

__device__ __forceinline__ void ph_dots(const Params& p, int tid) {
  int s = tid >> 6, lane = tid & 63;
  for (int task = blockIdx.x; task < 49 * 160; task += gridDim.x) {
    int o = task % 49, blk = task / 49;
    int b = blk / NBOU;
    int bd0 = p.bnd[blk * 2 + 0], bd1 = p.bnd[blk * 2 + 1];
    const float* cp = p.L0n + (((size_t)b * 224 + bd0) * 224 + bd1) * 1024;
    int Hs = 224 >> s;
    const float* base = (s == 0) ? p.L0n : (s == 1) ? p.L1 : (s == 2) ? p.L2 : p.L3;
    int yy = (bd0 >> s) + o / 7 - 3;
    int xx = (bd1 >> s) + o % 7 - 3;
    float a = 0.f;
    if (yy >= 0 && yy < Hs && xx >= 0 && xx < Hs) {
      const float* kp = base + (((size_t)b * Hs + yy) * Hs + xx) * 1024;
#pragma unroll
      for (int j = 0; j < 4; ++j) {
        int c = (lane + 64 * j) * 4;
        float4 kv = *(const float4*)(kp + c);
        float4 qv = *(const float4*)(cp + c);
        a += kv.x * qv.x + kv.y * qv.y + kv.z * qv.z + kv.w * qv.w;
      }
    }
    a = wave_red_sum(a);
    if (lane == 0) p.dots[blk * 196 + s * 49 + o] = a;
  }
}

__device__ __forceinline__ void ph_tokln(const Params& p, int tid,
                                         float* token, float* rbuf) {
  for (int blk = blockIdx.x; blk < 160; blk += gridDim.x) {
    int b = blk / NBOU, n = blk % NBOU;
    int bd0 = p.bnd[blk * 2 + 0], bd1 = p.bnd[blk * 2 + 1];
    const float* cp = p.L0n + (((size_t)b * 224 + bd0) * 224 + bd1) * 1024;
    {
      int d = tid * 4;
      *(float4*)&token[d] = *(const float4*)(cp + d);
    }
    if (tid < 196) token[1024 + tid] = p.dots[blk * 196 + tid];
    if (tid == 0) { token[1220] = (float)bd0; token[1221] = (float)bd1; }
    if (tid < 26) token[1222 + tid] = 0.f;
    __syncthreads();
    float ls = 0.f;
    for (int d = tid; d < DTOK; d += 256) ls += token[d];
    float mean = block_red_sum(ls, rbuf, tid) * (1.0f / DTOK);
    float lq = 0.f;
    for (int d = tid; d < DTOK; d += 256) { float t = token[d] - mean; lq += t * t; }
    float var = block_red_sum(lq, rbuf, tid) * (1.0f / DTOK);
    float rstd = rsqrtf(var + 1e-5f);
    for (int d = tid; d < DTOK; d += 256) {
      float o = (token[d] - mean) * rstd * p.lng[d] + p.lnb[d] + p.pe[n * DTOK + d];
      p.tokens[(size_t)blk * DTOK + d] = o;
      token[d] = o;
    }
    __syncthreads();
    frag_write_row(token, p.Af1, blk, T1c, tid);
    __syncthreads();
  }
}

__device__ __forceinline__ void ph_gemm(const short* __restrict__ Af,
                                        const short* __restrict__ Bf,
                                        float* __restrict__ partial,
                                        int T, int O, int S, int NT, int tid) {
  int w = tid >> 6, lane = tid & 63;
  int wr = w >> 1, wc = w & 1;
  int rl = lane & 15, kq = lane >> 4;
  const size_t bbase = (size_t)(wc * 2) * 512 + (size_t)lane * 8;
  const size_t abase = (size_t)(wr * 2) * 512 + (size_t)lane * 8;
  for (int task = blockIdx.x; task < NT * S; task += gridDim.x) {
    int nt = task % NT, sp = task / NT;
    int cps = (T + S - 1) / S;
    int t0 = sp * cps, t1 = min(t0 + cps, T);
    f32x4 acc[3][2][2];
#pragma unroll
    for (int mt = 0; mt < 3; ++mt)
#pragma unroll
      for (int mi = 0; mi < 2; ++mi)
#pragma unroll
        for (int ni = 0; ni < 2; ++ni) acc[mt][mi][ni] = (f32x4){0.f, 0.f, 0.f, 0.f};
    short8 bv[3][2], bv2[3][2];
#define LOADB(tt, BV)                                                          \
    {                                                                          \
      const short* bp = Bf + ((size_t)nt * T + (tt)) * 6144 + bbase;           \
      _Pragma("unroll")                                                        \
      for (int s = 0; s < 3; ++s)                                              \
        _Pragma("unroll")                                                      \
        for (int ni = 0; ni < 2; ++ni)                                         \
          BV[s][ni] = *(const short8*)(bp + s * 2048 + ni * 512);              \
    }
    if (t0 < t1) {
      LOADB(t0, bv);
      for (int t = t0; t < t1; ++t) {
        if (t + 1 < t1) LOADB(t + 1, bv2);
#pragma unroll
        for (int mt = 0; mt < 3; ++mt) {
          const short* ap = Af + ((size_t)(mt * T + t)) * 6144 + abase;
          short8 af[3][2];
#pragma unroll
          for (int s = 0; s < 3; ++s)
#pragma unroll
            for (int mi = 0; mi < 2; ++mi)
              af[s][mi] = *(const short8*)(ap + s * 2048 + mi * 512);
#pragma unroll
          for (int mi = 0; mi < 2; ++mi)
#pragma unroll
            for (int ni = 0; ni < 2; ++ni) {
              f32x4 a = acc[mt][mi][ni];
              a = __builtin_amdgcn_mfma_f32_16x16x32_bf16(af[0][mi], bv[0][ni], a, 0, 0, 0);
              a = __builtin_amdgcn_mfma_f32_16x16x32_bf16(af[0][mi], bv[1][ni], a, 0, 0, 0);
              a = __builtin_amdgcn_mfma_f32_16x16x32_bf16(af[1][mi], bv[0][ni], a, 0, 0, 0);
              a = __builtin_amdgcn_mfma_f32_16x16x32_bf16(af[0][mi], bv[2][ni], a, 0, 0, 0);
              a = __builtin_amdgcn_mfma_f32_16x16x32_bf16(af[2][mi], bv[0][ni], a, 0, 0, 0);
              a = __builtin_amdgcn_mfma_f32_16x16x32_bf16(af[1][mi], bv[1][ni], a, 0, 0, 0);
              acc[mt][mi][ni] = a;
            }
        }
#pragma unroll
        for (int s = 0; s < 3; ++s)
#pragma unroll
          for (int ni = 0; ni < 2; ++ni) bv[s][ni] = bv2[s][ni];
      }
    }
#undef LOADB
    float* pp = partial + (size_t)sp * MM * O;
#pragma unroll
    for (int mt = 0; mt < 3; ++mt)
#pragma unroll
      for (int mi = 0; mi < 2; ++mi)
#pragma unroll
        for (int ni = 0; ni < 2; ++ni) {
          int c = nt * 64 + wc * 32 + ni * 16 + rl;
          if (c >= O) continue;
#pragma unroll
          for (int reg = 0; reg < 4; ++reg) {
            int r = mt * 64 + wr * 32 + mi * 16 + kq * 4 + reg;
            if (r < MM) pp[(size_t)r * O + c] = acc[mt][mi][ni][reg];
          }
        }
  }
}

__device__ __forceinline__ void ph_red4(const Params& p, int tid) {
  const int O = OQKV, S = S_IPc;
  size_t total = (size_t)MM * O;
  size_t stride = (size_t)gridDim.x * 256 * 4;
  for (size_t idx = ((size_t)blockIdx.x * 256 + tid) * 4; idx < total; idx += stride) {
    float4 v = *(const float4*)(p.part + idx);
    for (int s = 1; s < S; ++s) {
      float4 q = *(const float4*)(p.part + (size_t)s * total + idx);
      v.x += q.x; v.y += q.y; v.z += q.z; v.w += q.w;
    }
    float r[4] = {v.x, v.y, v.z, v.w};
#pragma unroll
    for (int j = 0; j < 4; ++j) r[j] += p.ipb[(int)((idx + j) % O)];
    float4 wv = {r[0], r[1], r[2], r[3]};
    *(float4*)(p.qkvb + idx) = wv;
  }
}

__device__ __forceinline__ void ph_attn(const Params& p, int tid,
                                        float (*pv)[1248], float* sc) {
  int wave = tid >> 6, lane = tid & 63;
  for (int blk = blockIdx.x; blk < 160; blk += gridDim.x) {
    int b = blk / NBOU;
    float qr[20];
    const float* qrow = p.qkvb + (size_t)blk * OQKV;
#pragma unroll
    for (int j = 0; j < 20; ++j) {
      int d = lane + 64 * j;
      qr[j] = (d < DTOK) ? qrow[d] : 0.f;
    }
    for (int i = 0; i < 20; ++i) {
      int m2 = wave * 20 + i;
      const float* krow = p.qkvb + (size_t)(b * NBOU + m2) * OQKV + DTOK;
      float a = 0.f;
#pragma unroll
      for (int j = 0; j < 20; ++j) {
        int d = lane + 64 * j;
        if (d < DTOK) a += qr[j] * krow[d];
      }
      a = wave_red_sum(a);
      if (lane == 0) sc[m2] = a * (1.0f / 34.957116f);
    }
    __syncthreads();
    if (wave == 0) {
      float x0 = sc[lane];
      float x1 = (lane < 16) ? sc[64 + lane] : -INFINITY;
      float mx = fmaxf(x0, x1);
#pragma unroll
      for (int off = 32; off; off >>= 1) mx = fmaxf(mx, __shfl_xor(mx, off, 64));
      float e0 = expf(x0 - mx);
      float e1 = (lane < 16) ? expf(x1 - mx) : 0.f;
      float ssum = wave_red_sum(e0 + e1);
      sc[lane] = e0 / ssum;
      if (lane < 16) sc[64 + lane] = e1 / ssum;
    }
    __syncthreads();
    float acc[20];
#pragma unroll
    for (int j = 0; j < 20; ++j) acc[j] = 0.f;
    for (int i = 0; i < 20; ++i) {
      int m2 = wave * 20 + i;
      float pm = sc[m2];
      const float* vrow = p.qkvb + (size_t)(b * NBOU + m2) * OQKV + 2 * DTOK;
#pragma unroll
      for (int j = 0; j < 20; ++j) {
        int d = lane + 64 * j;
        if (d < DTOK) acc[j] += pm * vrow[d];
      }
    }
#pragma unroll
    for (int j = 0; j < 20; ++j) {
      int d = lane + 64 * j;
      if (d < DTOK) pv[wave][d] = acc[j];
    }
    __syncthreads();
    for (int d = tid; d < DTOK; d += 256)
      pv[0][d] = ((pv[0][d] + pv[1][d]) + pv[2][d]) + pv[3][d];
    if (tid < 26) pv[0][1222 + tid] = 0.f;
    __syncthreads();
    frag_write_row(pv[0], p.Af1, blk, T1c, tid);
    __syncthreads();
  }
}

__device__ __forceinline__ void ph_redln(const Params& p, int tid,
                                         float* row, float* rb) {
  const int O = DTOK, S = S_OPc;
  for (int m = blockIdx.x; m < 160; m += gridDim.x) {
    if (tid < 26) row[1222 + tid] = 0.f;
    float ls = 0.f;
    for (int d = tid; d < O; d += 256) {
      float v = 0.f;
      for (int s = 0; s < S; ++s) v += p.part[((size_t)s * MM + m) * O + d];
      v += p.opb[d];
      v += p.tokens[(size_t)m * O + d];
      row[d] = v; ls += v;
    }
    float mean = block_red_sum(ls, rb, tid) * (1.0f / DTOK);
    float lq = 0.f;
    for (int d = tid; d < O; d += 256) { float t = row[d] - mean; lq += t * t; }
    float var = block_red_sum(lq, rb, tid) * (1.0f / DTOK);
    float rstd = rsqrtf(var + 1e-5f);
    for (int d = tid; d < O; d += 256) {
      float xn = (row[d] - mean) * rstd * p.n1g[d] + p.n1b[d];
      p.x1[(size_t)m * O + d] = xn;
      row[d] = xn;
    }
    __syncthreads();
    frag_write_row(row, p.Af1, m, T1c, tid);
    __syncthreads();
  }
}

__device__ __forceinline__ void ph_redf(const Params& p, int tid) {
  const int O = FFD, S = S_L1c, T = T2c;
  size_t total = (size_t)MM * O;
  size_t stride = (size_t)gridDim.x * 256 * 8;
  for (size_t idx8 = ((size_t)blockIdx.x * 256 + tid) * 8; idx8 < total; idx8 += stride) {
    int r = (int)(idx8 / O), c = (int)(idx8 % O);
    float v[8];
#pragma unroll
    for (int j = 0; j < 8; ++j) v[j] = 0.f;
    for (int s = 0; s < S; ++s) {
      const float* q = p.part + (size_t)s * total + idx8;
#pragma unroll
      for (int j = 0; j < 8; ++j) v[j] += q[j];
    }
    short8 h, l, q8;
#pragma unroll
    for (int j = 0; j < 8; ++j) {
      float x = fmaxf(v[j] + p.l1b[c + j], 0.f);
      unsigned short hb = f2bf(x);
      float r1 = x - bf2f(hb);
      unsigned short lb = f2bf(r1);
      float r2 = r1 - bf2f(lb);
      h[j] = (short)hb; l[j] = (short)lb; q8[j] = (short)f2bf(r2);
    }
    int mt = r >> 6, mf = (r >> 4) & 3, rl = r & 15;
    int t = c >> 5, kq = (c >> 3) & 3;
    size_t base = (size_t)(mt * T + t) * 6144 + mf * 512 + (size_t)(rl + kq * 16) * 8;
    *(short8*)(p.Af2 + base) = h;
    *(short8*)(p.Af2 + base + 2048) = l;
    *(short8*)(p.Af2 + base + 4096) = q8;
  }
}

__device__ __forceinline__ void ph_redlnfc(const Params& p, int tid, int it,
                                           float* row, float* rb) {
  const int O = DTOK, S = S_L2c;
  for (int blk = blockIdx.x; blk < 160; blk += gridDim.x) {
    int n = blk % NBOU;
    float ls = 0.f;
    for (int d = tid; d < O; d += 256) {
      float v = 0.f;
      for (int s = 0; s < S; ++s) v += p.part[((size_t)s * MM + blk) * O + d];
      v += p.l2b[d];
      v += p.x1[(size_t)blk * O + d];
      row[d] = v; ls += v;
    }
    float mean = block_red_sum(ls, rb, tid) * (1.0f / DTOK);
    float lq = 0.f;
    for (int d = tid; d < O; d += 256) { float t = row[d] - mean; lq += t * t; }
    float var = block_red_sum(lq, rb, tid) * (1.0f / DTOK);
    float rstd = rsqrtf(var + 1e-5f);
    const float* w0 = p.fcw + (size_t)n * 1026 * DTOK;
    const float* w1 = w0 + DTOK;
    float s0 = 0.f, s1 = 0.f;
    for (int d = tid; d < O; d += 256) {
      float xn = (row[d] - mean) * rstd * p.n2g[d] + p.n2b[d];
      s0 += xn * w0[d];
      s1 += xn * w1[d];
    }
    s0 = block_red_sum(s0, rb, tid);
    s1 = block_red_sum(s1, rb, tid);
    if (tid == 0) {
      float o0 = s0 + p.fcb[n * 1026 + 0];
      float o1 = s1 + p.fcb[n * 1026 + 1];
      int b0 = p.bnd[blk * 2 + 0], b1 = p.bnd[blk * 2 + 1];
      int nb0 = b0 + (int)truncf(o0);
      int nb1 = b1 + (int)truncf(o1);
      nb0 = nb0 < 0 ? 0 : (nb0 > 223 ? 223 : nb0);
      nb1 = nb1 < 0 ? 0 : (nb1 > 223 ? 223 : nb1);
      p.bnd[blk * 2 + 0] = nb0;
      p.bnd[blk * 2 + 1] = nb1;
      p.outp[it * 320 + blk * 2 + 0] = nb0;
      p.outp[it * 320 + blk * 2 + 1] = nb1;
    }
    __syncthreads();
  }
}

// ================== cooperative mega kernel ==================
__global__ __launch_bounds__(256, 2) void k_mega(Params p) {
  cg::grid_group grid = cg::this_grid();
  __shared__ __align__(16) float smem4[4][1248];
  __shared__ float aux[96];
  int tid = threadIdx.x;
  for (int it = 0; it < 6; ++it) {
    ph_dots(p, tid);
    grid.sync();
    ph_tokln(p, tid, smem4[0], aux + 80);
    grid.sync();
    ph_gemm(p.Af1, p.ipWf, p.part, T1c, OQKV, S_IPc, NT_IPc, tid);
    grid.sync();
    ph_red4(p, tid);
    grid.sync();
    ph_attn(p, tid, smem4, aux);
    grid.sync();
    ph_gemm(p.Af1, p.opWf, p.part, T1c, DTOK, S_OPc, NT_OPc, tid);
    grid.sync();
    ph_redln(p, tid, smem4[0], aux + 80);
    grid.sync();
    ph_gemm(p.Af1, p.l1Wf, p.part, T1c, FFD, S_L1c, NT_L1c, tid);
    grid.sync();
    ph_redf(p, tid);
    grid.sync();
    ph_gemm(p.Af2, p.l2Wf, p.part, T2c, DTOK, S_L2c, NT_L2c, tid);
    grid.sync();
    ph_redlnfc(p, tid, it, smem4[0], aux + 80);
    grid.sync();
  }
}

// ================== fallback wrappers (round-9 path, same math) ==================
__global__ __launch_bounds__(256) void kw_dots(Params p) { ph_dots(p, threadIdx.x); }
__global__ __launch_bounds__(256) void kw_tokln(Params p) {
  __shared__ __align__(16) float token[1248];
  __shared__ float rbuf[8];
  ph_tokln(p, threadIdx.x, token, rbuf);
}
__global__ __launch_bounds__(256) void kw_gemm(Params p, int which) {
  const short* Af = (which == 3) ? p.Af2 : p.Af1;
  const short* Bf = (which == 0) ? p.ipWf : (which == 1) ? p.opWf : (which == 2) ? p.l1Wf : p.l2Wf;
  int T = (which == 3) ? T2c : T1c;
  int O = (which == 0) ? OQKV : (which == 2) ? FFD : DTOK;
  int S = (which == 0) ? S_IPc : (which == 1) ? S_OPc : (which == 2) ? S_L1c : S_L2c;
  int NT = (which == 0) ? NT_IPc : (which == 1) ? NT_OPc : (which == 2) ? NT_L1c : NT_L2c;
  ph_gemm(Af, Bf, p.part, T, O, S, NT, threadIdx.x);
}
__global__ __launch_bounds__(256) void kw_red4(Params p) { ph_red4(p, threadIdx.x); }
__global__ __launch_bounds__(256) void kw_attn(Params p) {
  __shared__ __align__(16) float pv[4][1248];
  __shared__ float sc[80];
  ph_attn(p, threadIdx.x, pv, sc);
}
__global__ __launch_bounds__(256) void kw_redln(Params p) {
  __shared__ __align__(16) float row[1248];
  __shared__ float rb[8];
  ph_redln(p, threadIdx.x, row, rb);
}
__global__ __launch_bounds__(256) void kw_redf(Params p) { ph_redf(p, threadIdx.x); }
__global__ __launch_bounds__(256) void kw_redlnfc(Params p, int it) {
  __shared__ __align__(16) float row[1248];
  __shared__ float rb[8];
  ph_redlnfc(p, threadIdx.x, it, row, rb);
}

extern "C" void kernel_launch(void* const* d_in, const int* in_sizes, int n_in,
                              void* d_out, int out_size, void* d_ws, size_t ws_size,
                              hipStream_t stream) {
  const float* f   = (const float*)d_in[0];
  const int*   pb  = (const int*)d_in[1];
  const float* lng = (const float*)d_in[2];
  const float* lnb = (const float*)d_in[3];
  const float* ipw = (const float*)d_in[4];
  const float* ipb = (const float*)d_in[5];
  const float* opw = (const float*)d_in[6];
  const float* opb = (const float*)d_in[7];
  const float* l1w = (const float*)d_in[8];
  const float* l1b = (const float*)d_in[9];
  const float* l2w = (const float*)d_in[10];
  const float* l2b = (const float*)d_in[11];
  const float* n1g = (const float*)d_in[12];
  const float* n1b = (const float*)d_in[13];
  const float* n2g = (const float*)d_in[14];
  const float* n2b = (const float*)d_in[15];
  const float* fcw = (const float*)d_in[16];
  const float* fcb = (const float*)d_in[17];
  int* outp = (int*)d_out;

  char* wsb = (char*)d_ws;
  auto alloc = [&](size_t bytes) -> char* {
    char* p = wsb;
    wsb += (bytes + 255) & ~(size_t)255;
    return p;
  };
  float* L0n  = (float*)alloc((size_t)2 * 224 * 224 * 1024 * 4);
  float* L1   = (float*)alloc((size_t)2 * 112 * 112 * 1024 * 4);
  float* L2   = (float*)alloc((size_t)2 * 56 * 56 * 1024 * 4);
  float* L3   = (float*)alloc((size_t)2 * 28 * 28 * 1024 * 4);
  float* pe   = (float*)alloc((size_t)NBOU * DTOK * 4);
  int*   bnd  = (int*)alloc(320 * 4);
  float* tokens = (float*)alloc((size_t)MM * DTOK * 4);
  float* qkvb   = (float*)alloc((size_t)MM * OQKV * 4);
  float* x1     = (float*)alloc((size_t)MM * DTOK * 4);
  float* dots   = (float*)alloc((size_t)MM * 196 * 4);
  short* Af1  = (short*)alloc((size_t)3 * T1c * 6144 * 2);
  short* Af2  = (short*)alloc((size_t)3 * T2c * 6144 * 2);
  short* ipWf = (short*)alloc((size_t)NT_IPc * T1c * 6144 * 2);
  short* opWf = (short*)alloc((size_t)NT_OPc * T1c * 6144 * 2);
  short* l1Wf = (short*)alloc((size_t)NT_L1c * T1c * 6144 * 2);
  short* l2Wf = (short*)alloc((size_t)NT_L2c * T2c * 6144 * 2);
  size_t partA = (size_t)S_L2c * MM * DTOK * 4;
  size_t partB = (size_t)S_IPc * MM * OQKV * 4;
  float* part = (float*)alloc(partA > partB ? partA : partB);

  k_nhwc0p<<<dim3(7, 112, 32), 256, 0, stream>>>(f, L0n, L1);
  k_pool23<<<dim3(28, 28, 2), 256, 0, stream>>>(L1, L2, L3);
  k_pe<<<NBOU, 256, 0, stream>>>(pe, bnd, pb);

  k_conv<<<NT_IPc * T1c, 256, 0, stream>>>(ipw, ipWf, OQKV, DTOK, T1c);
  k_conv<<<NT_OPc * T1c, 256, 0, stream>>>(opw, opWf, DTOK, DTOK, T1c);
  k_conv<<<NT_L1c * T1c, 256, 0, stream>>>(l1w, l1Wf, FFD, DTOK, T1c);
  k_conv<<<NT_L2c * T2c, 256, 0, stream>>>(l2w, l2Wf, DTOK, FFD, T2c);

  Params prm;
  prm.L0n = L0n; prm.L1 = L1; prm.L2 = L2; prm.L3 = L3;
  prm.lng = lng; prm.lnb = lnb; prm.pe = pe;
  prm.ipb = ipb; prm.opb = opb; prm.l1b = l1b; prm.l2b = l2b;
  prm.n1g = n1g; prm.n1b = n1b; prm.n2g = n2g; prm.n2b = n2b;
  prm.fcw = fcw; prm.fcb = fcb;
  prm.ipWf = ipWf; prm.opWf = opWf; prm.l1Wf = l1Wf; prm.l2Wf = l2Wf;
  prm.Af1 = Af1; prm.Af2 = Af2;
  prm.tokens = tokens; prm.qkvb = qkvb; prm.x1 = x1; prm.dots = dots; prm.part = part;
  prm.bnd = bnd; prm.outp = outp;

  // occupancy-derived cooperative grid; fall back to multi-kernel path on any failure
  int maxBlocksPerCU = 0;
  hipError_t occErr = hipOccupancyMaxActiveBlocksPerMultiprocessor(&maxBlocksPerCU, k_mega, 256, 0);
  bool coopOK = false;
  if (occErr == hipSuccess && maxBlocksPerCU >= 1) {
    int bpc = maxBlocksPerCU < 2 ? maxBlocksPerCU : 2;
    dim3 grid(bpc * 256);
    void* args[] = {&prm};
    hipError_t le = hipLaunchCooperativeKernel((const void*)k_mega, grid, dim3(256), args, 0, stream);
    if (le == hipSuccess) coopOK = true;
  }
  if (!coopOK) {
    for (int it = 0; it < 6; ++it) {
      kw_dots<<<49 * 160, 256, 0, stream>>>(prm);
      kw_tokln<<<160, 256, 0, stream>>>(prm);
      kw_gemm<<<NT_IPc * S_IPc, 256, 0, stream>>>(prm, 0);
      kw_red4<<<573, 256, 0, stream>>>(prm);
      kw_attn<<<160, 256, 0, stream>>>(prm);
      kw_gemm<<<NT_OPc * S_OPc, 256, 0, stream>>>(prm, 1);
      kw_redln<<<160, 256, 0, stream>>>(prm);
      kw_gemm<<<NT_L1c * S_L1c, 256, 0, stream>>>(prm, 2);
      kw_redf<<<160, 256, 0, stream>>>(prm);
      kw_gemm<<<NT_L2c * S_L2c, 256, 0, stream>>>(prm, 3);
      kw_redlnfc<<<160, 256, 0, stream>>>(prm, it);
    }
  }
}

// Round 12
// 1265.004 us; speedup vs baseline: 3.1910x; 3.1910x over previous
//
#include <hip/hip_runtime.h>
#include <math.h>

#define DTOK 1222
#define NBOU 80
#define MM   160
#define FFD  2048
#define OQKV 3666

typedef __attribute__((ext_vector_type(8))) short short8;
typedef __attribute__((ext_vector_type(4))) float f32x4;

// ---------- bf16 helpers ----------
__device__ __forceinline__ unsigned short f2bf(float x) {
  unsigned int u = __float_as_uint(x);
  unsigned int r = (u + 0x7FFFu + ((u >> 16) & 1u)) >> 16;
  return (unsigned short)r;
}
__device__ __forceinline__ float bf2f(unsigned short h) {
  return __uint_as_float((unsigned int)h << 16);
}

// ---------- reduction helpers ----------
__device__ __forceinline__ float wave_red_sum(float v) {
#pragma unroll
  for (int off = 32; off; off >>= 1) v += __shfl_xor(v, off, 64);
  return v;
}
__device__ __forceinline__ float block_red_sum(float v, float* rb, int tid) {
  v = wave_red_sum(v);
  __syncthreads();
  if ((tid & 63) == 0) rb[tid >> 6] = v;
  __syncthreads();
  return rb[0] + rb[1] + rb[2] + rb[3];
}

// ---------- frag-write: one row (r) of padded values in smem -> frag-linear splits ----------
__device__ __forceinline__ void frag_write_row(const float* __restrict__ row,
                                               short* __restrict__ Af,
                                               int r, int T, int tid) {
  int mt = r >> 6, mf = (r >> 4) & 3, rl = r & 15;
  for (int task = tid; task < T * 4; task += 256) {
    int t = task >> 2, kq = task & 3;
    const float* src = row + t * 32 + kq * 8;
    short8 h, l, q;
#pragma unroll
    for (int j = 0; j < 8; ++j) {
      float x = src[j];
      unsigned short hb = f2bf(x);
      float r1 = x - bf2f(hb);
      unsigned short lb = f2bf(r1);
      float r2 = r1 - bf2f(lb);
      h[j] = (short)hb; l[j] = (short)lb; q[j] = (short)f2bf(r2);
    }
    size_t base = (size_t)(mt * T + t) * 6144 + mf * 512 + (size_t)(rl + kq * 16) * 8;
    *(short8*)(Af + base) = h;
    *(short8*)(Af + base + 2048) = l;
    *(short8*)(Af + base + 4096) = q;
  }
}

// ---------- setup: fused NCHW->NHWC transpose (L0n) + 2x2 pool (L1), 64-ch tiles ----------
__global__ __launch_bounds__(256) void k_nhwc0p(const float* __restrict__ f,
                                                float* __restrict__ L0n,
                                                float* __restrict__ L1) {
  int xt = blockIdx.x, y1 = blockIdx.y, zc = blockIdx.z;
  int b = zc >> 4, ct = zc & 15;
  __shared__ float tile[64][65];
  int tid = threadIdx.x;
  const float* fb = f + (size_t)b * 1024 * 50176;
#pragma unroll
  for (int i = 0; i < 16; ++i) {
    int u = tid + 256 * i;
    int xl = u & 31, r = (u >> 5) & 1, c = u >> 6;
    tile[c][xl + 32 * r] = fb[(size_t)(ct * 64 + c) * 50176 +
                              (size_t)(2 * y1 + r) * 224 + xt * 32 + xl];
  }
  __syncthreads();
#pragma unroll
  for (int i = 0; i < 16; ++i) {
    int u = tid + 256 * i;
    int c2 = u & 63, x2 = (u >> 6) & 31, r2 = u >> 11;
    L0n[(((size_t)b * 224 + 2 * y1 + r2) * 224 + xt * 32 + x2) * 1024 + ct * 64 + c2] =
        tile[c2][x2 + 32 * r2];
  }
#pragma unroll
  for (int i = 0; i < 4; ++i) {
    int u = tid + 256 * i;
    int c3 = u & 63, xp = u >> 6;
    float v = 0.25f * (tile[c3][2 * xp] + tile[c3][2 * xp + 1] +
                       tile[c3][32 + 2 * xp] + tile[c3][32 + 2 * xp + 1]);
    L1[(((size_t)b * 112 + y1) * 112 + xt * 16 + xp) * 1024 + ct * 64 + c3] = v;
  }
}

// ---------- setup: fused L1 -> L2 and L3 (bitwise same as two-pass 2x2 pools) ----------
__global__ __launch_bounds__(256) void k_pool23(const float* __restrict__ L1,
                                                float* __restrict__ L2,
                                                float* __restrict__ L3) {
  int x3 = blockIdx.x, y3 = blockIdx.y, b = blockIdx.z;
  int c = threadIdx.x * 4;
  float4 l2v[2][2];
#pragma unroll
  for (int yy = 0; yy < 2; ++yy)
#pragma unroll
    for (int xx = 0; xx < 2; ++xx) {
      const float* p00 = L1 + (((size_t)(b * 112 + 4 * y3 + 2 * yy) * 112) + 4 * x3 + 2 * xx) * 1024 + c;
      const float* p01 = p00 + 1024;
      const float* p10 = p00 + (size_t)112 * 1024;
      const float* p11 = p10 + 1024;
      float4 a = *(const float4*)p00, bv = *(const float4*)p01;
      float4 cv = *(const float4*)p10, dv = *(const float4*)p11;
      float4 r;
      r.x = 0.25f * (a.x + bv.x + cv.x + dv.x);
      r.y = 0.25f * (a.y + bv.y + cv.y + dv.y);
      r.z = 0.25f * (a.z + bv.z + cv.z + dv.z);
      r.w = 0.25f * (a.w + bv.w + cv.w + dv.w);
      l2v[yy][xx] = r;
      *(float4*)(L2 + (((size_t)(b * 56 + 2 * y3 + yy) * 56) + 2 * x3 + xx) * 1024 + c) = r;
    }
  float4 r3;
  r3.x = 0.25f * (l2v[0][0].x + l2v[0][1].x + l2v[1][0].x + l2v[1][1].x);
  r3.y = 0.25f * (l2v[0][0].y + l2v[0][1].y + l2v[1][0].y + l2v[1][1].y);
  r3.z = 0.25f * (l2v[0][0].z + l2v[0][1].z + l2v[1][0].z + l2v[1][1].z);
  r3.w = 0.25f * (l2v[0][0].w + l2v[0][1].w + l2v[1][0].w + l2v[1][1].w);
  *(float4*)(L3 + (((size_t)(b * 28 + y3) * 28) + x3) * 1024 + c) = r3;
}

// ---------- setup: positional encoding + boundary init ----------
__global__ __launch_bounds__(256) void k_pe(float* __restrict__ pe, int* __restrict__ bnd,
                                            const int* __restrict__ pb) {
  int n = blockIdx.x, tid = threadIdx.x;
  for (int d = tid; d < DTOK; d += 256) {
    int i = d >> 1;
    double e = exp((double)(2 * i) * (-log(10000.0) / (double)DTOK));
    double ang = (double)n * e;
    pe[n * DTOK + d] = (float)((d & 1) ? cos(ang) : sin(ang));
  }
  if (n == 0) {
    for (int t = tid; t < 2 * NBOU * 2; t += 256) bnd[t] = pb[t];
  }
}

// ---------- weight conversion, all four weights in ONE dispatch ----------
// seg sizes: ip 58*39=2262, op 20*39=780, l1 32*39=1248, l2 20*64=1280 -> 5570 blocks
__global__ __launch_bounds__(256) void k_conv4(const float* __restrict__ ipw,
                                               const float* __restrict__ opw,
                                               const float* __restrict__ l1w,
                                               const float* __restrict__ l2w,
                                               short* __restrict__ ipWf,
                                               short* __restrict__ opWf,
                                               short* __restrict__ l1Wf,
                                               short* __restrict__ l2Wf) {
  int gb = blockIdx.x;
  const float* X; short* F; int R, K, T, b;
  if (gb < 2262)      { X = ipw; F = ipWf; R = OQKV; K = DTOK; T = 39; b = gb; }
  else if (gb < 3042) { X = opw; F = opWf; R = DTOK; K = DTOK; T = 39; b = gb - 2262; }
  else if (gb < 4290) { X = l1w; F = l1Wf; R = FFD;  K = DTOK; T = 39; b = gb - 3042; }
  else                { X = l2w; F = l2Wf; R = DTOK; K = FFD;  T = 64; b = gb - 4290; }
  int rt = b / T, t = b % T;
  int tid = threadIdx.x, mf = tid >> 6, lane = tid & 63;
  int row = rt * 64 + mf * 16 + (lane & 15);
  int k0 = t * 32 + (lane >> 4) * 8;
  float a[8];
#pragma unroll
  for (int j = 0; j < 8; ++j) {
    int k = k0 + j;
    a[j] = (row < R && k < K) ? X[(size_t)row * K + k] : 0.f;
  }
  short8 h, l, q;
#pragma unroll
  for (int j = 0; j < 8; ++j) {
    float x = a[j];
    unsigned short hb = f2bf(x);
    float r1 = x - bf2f(hb);
    unsigned short lb = f2bf(r1);
    float r2 = r1 - bf2f(lb);
    h[j] = (short)hb; l[j] = (short)lb; q[j] = (short)f2bf(r2);
  }
  size_t base = (size_t)b * 6144 + mf * 512 + (size_t)lane * 8;
  *(short8*)(F + base) = h;
  *(short8*)(F + base + 2048) = l;
  *(short8*)(F + base + 4096) = q;
}

// ---------- per-iteration: parallel neighborhood dots; block=(o, blk), wave=scale ----------
__global__ __launch_bounds__(256) void k_dots(const float* __restrict__ L0n,
                                              const float* __restrict__ L1,
                                              const float* __restrict__ L2,
                                              const float* __restrict__ L3,
                                              const int* __restrict__ bnd,
                                              float* __restrict__ dots) {
  int o = blockIdx.x;        // 0..48
  int blk = blockIdx.y;      // 0..159
  int b = blk / NBOU;
  int tid = threadIdx.x, s = tid >> 6, lane = tid & 63;
  int bd0 = bnd[blk * 2 + 0], bd1 = bnd[blk * 2 + 1];
  const float* cp = L0n + (((size_t)b * 224 + bd0) * 224 + bd1) * 1024;
  int Hs = 224 >> s;
  const float* base = (s == 0) ? L0n : (s == 1) ? L1 : (s == 2) ? L2 : L3;
  int yy = (bd0 >> s) + o / 7 - 3;
  int xx = (bd1 >> s) + o % 7 - 3;
  float a = 0.f;
  if (yy >= 0 && yy < Hs && xx >= 0 && xx < Hs) {
    const float* kp = base + (((size_t)b * Hs + yy) * Hs + xx) * 1024;
#pragma unroll
    for (int j = 0; j < 4; ++j) {
      int c = (lane + 64 * j) * 4;
      float4 kv = *(const float4*)(kp + c);
      float4 qv = *(const float4*)(cp + c);
      a += kv.x * qv.x + kv.y * qv.y + kv.z * qv.z + kv.w * qv.w;
    }
  }
  a = wave_red_sum(a);
  if (lane == 0) dots[blk * 196 + s * 49 + o] = a;
}

// ---------- per-iteration: token assemble + LN + pe -> tokens fp32 + Af frags ----------
__global__ __launch_bounds__(256) void k_tokln(const float* __restrict__ L0n,
                                               const int* __restrict__ bnd,
                                               const float* __restrict__ dots,
                                               const float* __restrict__ g,
                                               const float* __restrict__ bb,
                                               const float* __restrict__ pe,
                                               float* __restrict__ tok_out,
                                               short* __restrict__ Af, int T) {
  int blk = blockIdx.x;
  int b = blk / NBOU, n = blk % NBOU;
  int tid = threadIdx.x;
  __shared__ __align__(16) float token[1248];
  __shared__ float rbuf[8];
  int bd0 = bnd[blk * 2 + 0], bd1 = bnd[blk * 2 + 1];
  const float* cp = L0n + (((size_t)b * 224 + bd0) * 224 + bd1) * 1024;
  {
    int d = tid * 4;
    *(float4*)&token[d] = *(const float4*)(cp + d);
  }
  if (tid < 196) token[1024 + tid] = dots[blk * 196 + tid];
  if (tid == 0) { token[1220] = (float)bd0; token[1221] = (float)bd1; }
  if (tid < 26) token[1222 + tid] = 0.f;
  __syncthreads();

  float ls = 0.f;
  for (int d = tid; d < DTOK; d += 256) ls += token[d];
  float mean = block_red_sum(ls, rbuf, tid) * (1.0f / DTOK);
  float lq = 0.f;
  for (int d = tid; d < DTOK; d += 256) { float t = token[d] - mean; lq += t * t; }
  float var = block_red_sum(lq, rbuf, tid) * (1.0f / DTOK);
  float rstd = rsqrtf(var + 1e-5f);
  for (int d = tid; d < DTOK; d += 256) {
    float o = (token[d] - mean) * rstd * g[d] + bb[d] + pe[n * DTOK + d];
    tok_out[(size_t)blk * DTOK + d] = o;
    token[d] = o;
  }
  __syncthreads();
  frag_write_row(token, Af, blk, T, tid);
}

// ---------- MFMA split-K GEMM: A and B both frag-linear; full M per block ----------
__global__ __launch_bounds__(256) void k_mfma2(const short* __restrict__ Af,
                                               const short* __restrict__ Bf,
                                               float* __restrict__ partial,
                                               int T, int O, int S) {
  int nt = blockIdx.x, sp = blockIdx.y;
  int tid = threadIdx.x, w = tid >> 6, lane = tid & 63;
  int wr = w >> 1, wc = w & 1;
  int rl = lane & 15, kq = lane >> 4;
  int cps = (T + S - 1) / S;
  int t0 = sp * cps, t1 = min(t0 + cps, T);

  f32x4 acc[3][2][2];
#pragma unroll
  for (int mt = 0; mt < 3; ++mt)
#pragma unroll
    for (int mi = 0; mi < 2; ++mi)
#pragma unroll
      for (int ni = 0; ni < 2; ++ni) acc[mt][mi][ni] = (f32x4){0.f, 0.f, 0.f, 0.f};

  const size_t bbase = (size_t)(wc * 2) * 512 + (size_t)lane * 8;
  const size_t abase = (size_t)(wr * 2) * 512 + (size_t)lane * 8;

  short8 bv[3][2], bv2[3][2];

#define LOADB(tt, BV)                                                          \
  {                                                                            \
    const short* bp = Bf + ((size_t)nt * T + (tt)) * 6144 + bbase;             \
    _Pragma("unroll")                                                          \
    for (int s = 0; s < 3; ++s)                                                \
      _Pragma("unroll")                                                        \
      for (int ni = 0; ni < 2; ++ni)                                           \
        BV[s][ni] = *(const short8*)(bp + s * 2048 + ni * 512);                \
  }

  if (t0 < t1) {
    LOADB(t0, bv);
    for (int t = t0; t < t1; ++t) {
      if (t + 1 < t1) LOADB(t + 1, bv2);
#pragma unroll
      for (int mt = 0; mt < 3; ++mt) {
        const short* ap = Af + ((size_t)(mt * T + t)) * 6144 + abase;
        short8 af[3][2];
#pragma unroll
        for (int s = 0; s < 3; ++s)
#pragma unroll
          for (int mi = 0; mi < 2; ++mi)
            af[s][mi] = *(const short8*)(ap + s * 2048 + mi * 512);
#pragma unroll
        for (int mi = 0; mi < 2; ++mi)
#pragma unroll
          for (int ni = 0; ni < 2; ++ni) {
            f32x4 a = acc[mt][mi][ni];
            a = __builtin_amdgcn_mfma_f32_16x16x32_bf16(af[0][mi], bv[0][ni], a, 0, 0, 0); // hh
            a = __builtin_amdgcn_mfma_f32_16x16x32_bf16(af[0][mi], bv[1][ni], a, 0, 0, 0); // hl
            a = __builtin_amdgcn_mfma_f32_16x16x32_bf16(af[1][mi], bv[0][ni], a, 0, 0, 0); // lh
            a = __builtin_amdgcn_mfma_f32_16x16x32_bf16(af[0][mi], bv[2][ni], a, 0, 0, 0); // h3
            a = __builtin_amdgcn_mfma_f32_16x16x32_bf16(af[2][mi], bv[0][ni], a, 0, 0, 0); // 3h
            a = __builtin_amdgcn_mfma_f32_16x16x32_bf16(af[1][mi], bv[1][ni], a, 0, 0, 0); // ll
            acc[mt][mi][ni] = a;
          }
      }
#pragma unroll
      for (int s = 0; s < 3; ++s)
#pragma unroll
        for (int ni = 0; ni < 2; ++ni) bv[s][ni] = bv2[s][ni];
    }
  }
#undef LOADB

  float* pp = partial + (size_t)sp * MM * O;
#pragma unroll
  for (int mt = 0; mt < 3; ++mt)
#pragma unroll
    for (int mi = 0; mi < 2; ++mi)
#pragma unroll
      for (int ni = 0; ni < 2; ++ni) {
        int c = nt * 64 + wc * 32 + ni * 16 + rl;
        if (c >= O) continue;
#pragma unroll
        for (int reg = 0; reg < 4; ++reg) {
          int r = mt * 64 + wr * 32 + mi * 16 + kq * 4 + reg;
          if (r < MM) pp[(size_t)r * O + c] = acc[mt][mi][ni][reg];
        }
      }
}

// ---------- parallel split-K reduce + bias (fp32 out, for qkv) ----------
__global__ __launch_bounds__(256) void k_red4(const float* __restrict__ partial,
                                              const float* __restrict__ bias,
                                              float* __restrict__ out,
                                              int O, int S) {
  size_t idx = ((size_t)blockIdx.x * 256 + threadIdx.x) * 4;
  size_t total = (size_t)MM * O;
  if (idx >= total) return;
  float4 v = *(const float4*)(partial + idx);
  for (int s = 1; s < S; ++s) {
    float4 p = *(const float4*)(partial + (size_t)s * total + idx);
    v.x += p.x; v.y += p.y; v.z += p.z; v.w += p.w;
  }
  float r[4] = {v.x, v.y, v.z, v.w};
#pragma unroll
  for (int j = 0; j < 4; ++j) r[j] += bias[(int)((idx + j) % O)];
  float4 wv = {r[0], r[1], r[2], r[3]};
  *(float4*)(out + idx) = wv;
}

// ---------- split-K reduce + bias + relu -> frag only (lin1 -> hb frags) ----------
__global__ __launch_bounds__(256) void k_redf(const float* __restrict__ partial,
                                              const float* __restrict__ bias,
                                              short* __restrict__ Af,
                                              int S, int T) {
  const int O = FFD;
  size_t idx8 = ((size_t)blockIdx.x * 256 + threadIdx.x) * 8;
  size_t total = (size_t)MM * O;
  if (idx8 >= total) return;
  int r = (int)(idx8 / O), c = (int)(idx8 % O);
  float v[8];
#pragma unroll
  for (int j = 0; j < 8; ++j) v[j] = 0.f;
  for (int s = 0; s < S; ++s) {
    const float* p = partial + (size_t)s * total + idx8;
#pragma unroll
    for (int j = 0; j < 8; ++j) v[j] += p[j];
  }
  short8 h, l, q;
#pragma unroll
  for (int j = 0; j < 8; ++j) {
    float x = fmaxf(v[j] + bias[c + j], 0.f);
    unsigned short hb = f2bf(x);
    float r1 = x - bf2f(hb);
    unsigned short lb = f2bf(r1);
    float r2 = r1 - bf2f(lb);
    h[j] = (short)hb; l[j] = (short)lb; q[j] = (short)f2bf(r2);
  }
  int mt = r >> 6, mf = (r >> 4) & 3, rl = r & 15;
  int t = c >> 5, kq = (c >> 3) & 3;
  size_t base = (size_t)(mt * T + t) * 6144 + mf * 512 + (size_t)(rl + kq * 16) * 8;
  *(short8*)(Af + base) = h;
  *(short8*)(Af + base + 2048) = l;
  *(short8*)(Af + base + 4096) = q;
}

// ---------- split-K reduce + bias + residual + LN -> x1 fp32 + Af frags ----------
__global__ __launch_bounds__(256) void k_redln(const float* __restrict__ partial,
                                               const float* __restrict__ bias,
                                               const float* __restrict__ res,
                                               const float* __restrict__ g,
                                               const float* __restrict__ bb,
                                               float* __restrict__ xout,
                                               short* __restrict__ Af,
                                               int S, int T) {
  const int O = DTOK;
  int m = blockIdx.x, tid = threadIdx.x;
  __shared__ __align__(16) float row[1248];
  __shared__ float rb[8];
  if (tid < 26) row[1222 + tid] = 0.f;
  float ls = 0.f;
  for (int d = tid; d < O; d += 256) {
    float v = 0.f;
    for (int s = 0; s < S; ++s) v += partial[((size_t)s * MM + m) * O + d];
    v += bias[d];
    v += res[(size_t)m * O + d];
    row[d] = v; ls += v;
  }
  float mean = block_red_sum(ls, rb, tid) * (1.0f / DTOK);
  float lq = 0.f;
  for (int d = tid; d < O; d += 256) { float t = row[d] - mean; lq += t * t; }
  float var = block_red_sum(lq, rb, tid) * (1.0f / DTOK);
  float rstd = rsqrtf(var + 1e-5f);
  for (int d = tid; d < O; d += 256) {
    float xn = (row[d] - mean) * rstd * g[d] + bb[d];
    xout[(size_t)m * O + d] = xn;
    row[d] = xn;
  }
  __syncthreads();
  frag_write_row(row, Af, m, T, tid);
}

// ---------- split-K reduce + bias + residual + LN + fc head + boundary update ----------
__global__ __launch_bounds__(256) void k_redlnfc(const float* __restrict__ partial,
                                                 const float* __restrict__ bias,
                                                 const float* __restrict__ res,
                                                 const float* __restrict__ g,
                                                 const float* __restrict__ bb,
                                                 const float* __restrict__ fcw,
                                                 const float* __restrict__ fcb,
                                                 int* __restrict__ bnd,
                                                 int* __restrict__ outp,
                                                 int S) {
  const int O = DTOK;
  int blk = blockIdx.x;
  int n = blk % NBOU;
  int tid = threadIdx.x;
  __shared__ float row[DTOK];
  __shared__ float rb[8];
  float ls = 0.f;
  for (int d = tid; d < O; d += 256) {
    float v = 0.f;
    for (int s = 0; s < S; ++s) v += partial[((size_t)s * MM + blk) * O + d];
    v += bias[d];
    v += res[(size_t)blk * O + d];
    row[d] = v; ls += v;
  }
  float mean = block_red_sum(ls, rb, tid) * (1.0f / DTOK);
  float lq = 0.f;
  for (int d = tid; d < O; d += 256) { float t = row[d] - mean; lq += t * t; }
  float var = block_red_sum(lq, rb, tid) * (1.0f / DTOK);
  float rstd = rsqrtf(var + 1e-5f);
  const float* w0 = fcw + (size_t)n * 1026 * DTOK;
  const float* w1 = w0 + DTOK;
  float s0 = 0.f, s1 = 0.f;
  for (int d = tid; d < O; d += 256) {
    float xn = (row[d] - mean) * rstd * g[d] + bb[d];
    s0 += xn * w0[d];
    s1 += xn * w1[d];
  }
  s0 = block_red_sum(s0, rb, tid);
  s1 = block_red_sum(s1, rb, tid);
  if (tid == 0) {
    float o0 = s0 + fcb[n * 1026 + 0];
    float o1 = s1 + fcb[n * 1026 + 1];
    int b0 = bnd[blk * 2 + 0], b1 = bnd[blk * 2 + 1];
    int nb0 = b0 + (int)truncf(o0);
    int nb1 = b1 + (int)truncf(o1);
    nb0 = nb0 < 0 ? 0 : (nb0 > 223 ? 223 : nb0);
    nb1 = nb1 < 0 ? 0 : (nb1 > 223 ? 223 : nb1);
    bnd[blk * 2 + 0] = nb0;
    bnd[blk * 2 + 1] = nb1;
    outp[blk * 2 + 0] = nb0;
    outp[blk * 2 + 1] = nb1;
  }
}

// ---------- fused attention: scores + softmax + PV + frag-write (512 threads) ----------
__global__ __launch_bounds__(512) void k_attn3(const float* __restrict__ qkv,
                                               short* __restrict__ Af, int T) {
  int blk = blockIdx.x;
  int b = blk / NBOU;
  int tid = threadIdx.x, w = tid >> 6, lane = tid & 63;
  __shared__ __align__(16) float q[1224];
  __shared__ float sc[80];
  __shared__ __align__(16) float pv[8][1248];
  const float* qrow = qkv + (size_t)blk * OQKV;
  for (int d = tid; d < DTOK; d += 512) q[d] = qrow[d];
  __syncthreads();

#pragma unroll
  for (int i = 0; i < 10; ++i) {
    int m2 = w * 10 + i;
    const float* krow = qkv + (size_t)(b * NBOU + m2) * OQKV + DTOK;
    float a = 0.f;
#pragma unroll
    for (int j = 0; j < 20; ++j) {
      int d = lane + 64 * j;
      if (d < DTOK) a += q[d] * krow[d];
    }
    a = wave_red_sum(a);
    if (lane == 0) sc[m2] = a * (1.0f / 34.957116f);  // 1/sqrt(1222)
  }
  __syncthreads();
  if (w == 0) {
    float x0 = sc[lane];
    float x1 = (lane < 16) ? sc[64 + lane] : -INFINITY;
    float mx = fmaxf(x0, x1);
#pragma unroll
    for (int off = 32; off; off >>= 1) mx = fmaxf(mx, __shfl_xor(mx, off, 64));
    float e0 = expf(x0 - mx);
    float e1 = (lane < 16) ? expf(x1 - mx) : 0.f;
    float ssum = wave_red_sum(e0 + e1);
    sc[lane] = e0 / ssum;
    if (lane < 16) sc[64 + lane] = e1 / ssum;
  }
  __syncthreads();

  float acc[20];
#pragma unroll
  for (int j = 0; j < 20; ++j) acc[j] = 0.f;
  for (int i = 0; i < 10; ++i) {
    int m2 = w * 10 + i;
    float pm = sc[m2];
    const float* vrow = qkv + (size_t)(b * NBOU + m2) * OQKV + 2 * DTOK;
#pragma unroll
    for (int j = 0; j < 20; ++j) {
      int d = lane + 64 * j;
      if (d < DTOK) acc[j] += pm * vrow[d];
    }
  }
#pragma unroll
  for (int j = 0; j < 20; ++j) {
    int d = lane + 64 * j;
    if (d < DTOK) pv[w][d] = acc[j];
  }
  __syncthreads();
  for (int d = tid; d < DTOK; d += 512) {
    float v = pv[0][d];
#pragma unroll
    for (int s = 1; s < 8; ++s) v += pv[s][d];
    pv[0][d] = v;
  }
  if (tid < 26) pv[0][1222 + tid] = 0.f;
  __syncthreads();
  frag_write_row(pv[0], Af, blk, T, tid);
}

extern "C" void kernel_launch(void* const* d_in, const int* in_sizes, int n_in,
                              void* d_out, int out_size, void* d_ws, size_t ws_size,
                              hipStream_t stream) {
  const float* f   = (const float*)d_in[0];
  const int*   pb  = (const int*)d_in[1];
  const float* lng = (const float*)d_in[2];
  const float* lnb = (const float*)d_in[3];
  const float* ipw = (const float*)d_in[4];
  const float* ipb = (const float*)d_in[5];
  const float* opw = (const float*)d_in[6];
  const float* opb = (const float*)d_in[7];
  const float* l1w = (const float*)d_in[8];
  const float* l1b = (const float*)d_in[9];
  const float* l2w = (const float*)d_in[10];
  const float* l2b = (const float*)d_in[11];
  const float* n1g = (const float*)d_in[12];
  const float* n1b = (const float*)d_in[13];
  const float* n2g = (const float*)d_in[14];
  const float* n2b = (const float*)d_in[15];
  const float* fcw = (const float*)d_in[16];
  const float* fcb = (const float*)d_in[17];
  int* outp = (int*)d_out;

  const int T1 = 39;   // ceil(1222/32)
  const int T2 = 64;   // 2048/32
  const int NT_IP = 58, NT_OP = 20, NT_L1 = 32, NT_L2 = 20;
  const int S_IP = 6, S_OP = 10, S_L1 = 8, S_L2 = 16;

  char* wsb = (char*)d_ws;
  auto alloc = [&](size_t bytes) -> char* {
    char* p = wsb;
    wsb += (bytes + 255) & ~(size_t)255;
    return p;
  };
  float* L0n  = (float*)alloc((size_t)2 * 224 * 224 * 1024 * 4);
  float* L1   = (float*)alloc((size_t)2 * 112 * 112 * 1024 * 4);
  float* L2   = (float*)alloc((size_t)2 * 56 * 56 * 1024 * 4);
  float* L3   = (float*)alloc((size_t)2 * 28 * 28 * 1024 * 4);
  float* pe   = (float*)alloc((size_t)NBOU * DTOK * 4);
  int*   bnd  = (int*)alloc(320 * 4);
  float* tokens = (float*)alloc((size_t)MM * DTOK * 4);
  float* qkvb   = (float*)alloc((size_t)MM * OQKV * 4);
  float* x1     = (float*)alloc((size_t)MM * DTOK * 4);
  float* dots   = (float*)alloc((size_t)MM * 196 * 4);
  short* Af1  = (short*)alloc((size_t)3 * T1 * 6144 * 2);
  short* Af2  = (short*)alloc((size_t)3 * T2 * 6144 * 2);
  short* ipWf = (short*)alloc((size_t)NT_IP * T1 * 6144 * 2);
  short* opWf = (short*)alloc((size_t)NT_OP * T1 * 6144 * 2);
  short* l1Wf = (short*)alloc((size_t)NT_L1 * T1 * 6144 * 2);
  short* l2Wf = (short*)alloc((size_t)NT_L2 * T2 * 6144 * 2);
  float* part = (float*)alloc((size_t)S_IP * MM * OQKV * 4);

  k_nhwc0p<<<dim3(7, 112, 32), 256, 0, stream>>>(f, L0n, L1);
  k_pool23<<<dim3(28, 28, 2), 256, 0, stream>>>(L1, L2, L3);
  k_pe<<<NBOU, 256, 0, stream>>>(pe, bnd, pb);

  k_conv4<<<5570, 256, 0, stream>>>(ipw, opw, l1w, l2w, ipWf, opWf, l1Wf, l2Wf);

  for (int it = 0; it < 6; ++it) {
    k_dots<<<dim3(49, 160), 256, 0, stream>>>(L0n, L1, L2, L3, bnd, dots);
    k_tokln<<<160, 256, 0, stream>>>(L0n, bnd, dots, lng, lnb, pe, tokens, Af1, T1);

    // in_proj -> qkvb
    k_mfma2<<<dim3(NT_IP, S_IP), 256, 0, stream>>>(Af1, ipWf, part, T1, OQKV, S_IP);
    k_red4<<<(MM * OQKV + 1023) / 1024, 256, 0, stream>>>(part, ipb, qkvb, OQKV, S_IP);

    k_attn3<<<160, 512, 0, stream>>>(qkvb, Af1, T1);

    // out_proj + tokens residual + norm1 -> x1 (+frags)
    k_mfma2<<<dim3(NT_OP, S_OP), 256, 0, stream>>>(Af1, opWf, part, T1, DTOK, S_OP);
    k_redln<<<160, 256, 0, stream>>>(part, opb, tokens, n1g, n1b, x1, Af1, S_OP, T1);

    // lin1 (relu) -> hb frags
    k_mfma2<<<dim3(NT_L1, S_L1), 256, 0, stream>>>(Af1, l1Wf, part, T1, FFD, S_L1);
    k_redf<<<MM * FFD / 2048, 256, 0, stream>>>(part, l1b, Af2, S_L1, T2);

    // lin2 + x1 residual + norm2 + fc head
    k_mfma2<<<dim3(NT_L2, S_L2), 256, 0, stream>>>(Af2, l2Wf, part, T2, DTOK, S_L2);
    k_redlnfc<<<160, 256, 0, stream>>>(part, l2b, x1, n2g, n2b, fcw, fcb, bnd, outp + it * 320, S_L2);
  }
}